// Round 7
// baseline (152.372 us; speedup 1.0000x reference)
//
#include <hip/hip_runtime.h>

#define B_ 4
#define T_ 4096
#define C_ 1024
#define H_ 64

typedef _Float16 half8  __attribute__((ext_vector_type(8)));
typedef _Float16 half4_ __attribute__((ext_vector_type(4)));
typedef float    floatx4 __attribute__((ext_vector_type(4)));

#define MFMA16(a, b, c) __builtin_amdgcn_mfma_f32_16x16x32_f16(a, b, c, 0, 0, 0)

// ---------------------------------------------------------------------------
// Kernel 1: pack W into MFMA-fragment order (lane-contiguous A-frags):
// Wt2[(((mt*16 + j)*2 + f)*64 + lane)*8 + jj] <- W[k][h'],
//   k = j*64 + f*32 + (lane>>4)*8 + jj,  h' = mt*16 + (lane&15)  (mt 0..11)
// ---------------------------------------------------------------------------
__global__ __launch_bounds__(256) void pack_w_kn(
    const float* __restrict__ Wq, const float* __restrict__ Wk,
    const float* __restrict__ Wv, _Float16* __restrict__ Wt2)
{
    const int idx  = blockIdx.x * 256 + threadIdx.x;  // 0 .. 196607
    const int mt   = idx >> 14;
    const int j    = (idx >> 10) & 15;
    const int f    = (idx >> 9) & 1;
    const int lane = (idx >> 3) & 63;
    const int jj   = idx & 7;
    const int q = lane >> 4, c = lane & 15;
    const int k  = j * 64 + f * 32 + q * 8 + jj;
    const int hp = mt * 16 + c;                       // 0..191
    const float* W = (hp < 64) ? Wq : (hp < 128) ? Wk : Wv;
    Wt2[idx] = (_Float16)W[k * H_ + (hp & 63)];
}

// ---------------------------------------------------------------------------
// Kernel 2: fused QKV projection.  Block = 256 thr (4 waves), BM=32 rows,
// 16 K-steps of 64, x dbuf-staged in LDS.  Wave = m-group (3 m-tiles) and
// covers BOTH 16-row n-halves: each A-frag pair feeds 4 MFMAs (12/step/wave)
// -> halves Wt2 L2 traffic vs round 6, doubles ILP.  512 blocks = 4/CU.
// Outputs: Qh row-major; K/V in per-64-key-tile fragment-packed layouts.
// ---------------------------------------------------------------------------
__global__ __launch_bounds__(256, 4) void qkv_kn(
    const float* __restrict__ x, const _Float16* __restrict__ Wt2,
    _Float16* __restrict__ Qh, _Float16* __restrict__ Kpk,
    _Float16* __restrict__ Vpk)
{
    __shared__ _Float16 xs[2][32][72];                // 9216 B
    const int tid  = threadIdx.x;
    const int lane = tid & 63, w = tid >> 6;          // w = m-group 0..3
    const int q    = lane >> 4, c = lane & 15;
    const int row0 = blockIdx.x * 32;

    // staging: 512 float4/step, 2 per thread (rows r1 and r1+16)
    const int r1 = tid >> 4, c1 = (tid & 15) * 4;
    const float* xg1 = x + (size_t)(row0 + r1) * C_ + c1;
    const float* xg2 = xg1 + 16 * C_;

    floatx4 acc[3][2];
    #pragma unroll
    for (int i = 0; i < 3; ++i)
        #pragma unroll
        for (int n = 0; n < 2; ++n) acc[i][n] = floatx4{0.f, 0.f, 0.f, 0.f};

    float4 g1 = *(const float4*)xg1;                  // preload step 0
    float4 g2 = *(const float4*)xg2;

    for (int j = 0; j < 16; ++j) {
        half4_ h1, h2;
        h1[0] = (_Float16)g1.x; h1[1] = (_Float16)g1.y;
        h1[2] = (_Float16)g1.z; h1[3] = (_Float16)g1.w;
        h2[0] = (_Float16)g2.x; h2[1] = (_Float16)g2.y;
        h2[2] = (_Float16)g2.z; h2[3] = (_Float16)g2.w;
        *(half4_*)(&xs[j & 1][r1][c1])      = h1;
        *(half4_*)(&xs[j & 1][r1 + 16][c1]) = h2;
        __syncthreads();
        if (j < 15) {
            g1 = *(const float4*)(xg1 + (j + 1) * 64);
            g2 = *(const float4*)(xg2 + (j + 1) * 64);
        }

        // B-frags for both n-halves (pad-72 LDS -> 2-way banks, free)
        const half8 b0 = *(const half8*)(&xs[j & 1][c][q * 8]);
        const half8 b1 = *(const half8*)(&xs[j & 1][c][32 + q * 8]);
        const half8 b2 = *(const half8*)(&xs[j & 1][16 + c][q * 8]);
        const half8 b3 = *(const half8*)(&xs[j & 1][16 + c][32 + q * 8]);

        // A-frags: 6 lane-contiguous 1-KB loads; each feeds 2 MFMAs
        #pragma unroll
        for (int i = 0; i < 3; ++i) {
            const size_t fb = ((size_t)((w * 3 + i) * 16 + j) * 2) * 512 + lane * 8;
            const half8 a0 = *(const half8*)(Wt2 + fb);
            const half8 a1 = *(const half8*)(Wt2 + fb + 512);
            acc[i][0] = MFMA16(a0, b0, acc[i][0]);
            acc[i][0] = MFMA16(a1, b1, acc[i][0]);
            acc[i][1] = MFMA16(a0, b2, acc[i][1]);
            acc[i][1] = MFMA16(a1, b3, acc[i][1]);
        }
    }

    // epilogue: acc[i][n][r] = C^T[h'=(w*3+i)*16+q*4+r][row0+n*16+c]
    #pragma unroll
    for (int n = 0; n < 2; ++n) {
        const int row = row0 + n * 16 + c;
        const int b = row >> 12, t4 = row & (T_ - 1);
        const int kt = t4 >> 6;
        const size_t tbase = ((size_t)b * 64 + kt) * 4096;
        const int mtk = (t4 >> 4) & 3;                // key-tile m-row group
        const int kk  = t4 & 63;                      // key pos in tile
        #pragma unroll
        for (int i = 0; i < 3; ++i) {
            const int gi = w * 3 + i;                 // m-tile 0..11
            if (gi < 4) {                             // Q row-major
                half4_ v;
                #pragma unroll
                for (int r = 0; r < 4; ++r) v[r] = (_Float16)acc[i][n][r];
                *(half4_*)(Qh + (size_t)row * H_ + gi * 16 + q * 4) = v;
            } else if (gi < 8) {                      // K fragment-packed
                half4_ v;
                #pragma unroll
                for (int r = 0; r < 4; ++r) v[r] = (_Float16)acc[i][n][r];
                const int e  = gi - 4;                // h = e*16 + q*4 + r
                const int f  = e >> 1;
                const int qa = (e * 2 + (q >> 1)) & 3;
                *(half4_*)(Kpk + tbase
                           + ((size_t)(mtk * 2 + f) * 64 + qa * 16 + c) * 8
                           + (q & 1) * 4) = v;
            } else {                                  // V fragment-packed
                const int mtv = gi - 8;
                const int qa = (kk >> 3) & 3, fv = kk >> 5, jv = kk & 7;
                #pragma unroll
                for (int r = 0; r < 4; ++r) {
                    const int cv = q * 4 + r;         // h & 15
                    Vpk[tbase + ((size_t)(mtv * 2 + fv) * 64 + qa * 16 + cv) * 8
                        + jv] = (_Float16)acc[i][n][r];
                }
            }
        }
    }
}

// ---------------------------------------------------------------------------
// Kernel 3: causal flash attention.  Block = 32 q-rows (two 16-row n-tiles
// sharing K/V frag loads -> half the L2 traffic of round 6), 512 thr,
// 8-way split-K.  Fragment-packed K/V: every load = base + lane*16.
// Single-buffer wave-private P (DS in-order per wave => WAR safe).
// Two-phase LDS flash combine (overlaid on P region).
// ---------------------------------------------------------------------------
__global__ __launch_bounds__(512, 3) void attn_kn(
    const _Float16* __restrict__ Qh, const _Float16* __restrict__ Kpk,
    const _Float16* __restrict__ Vpk, float* __restrict__ out)
{
    __shared__ __align__(16) char smem[36864];
    const int lane = threadIdx.x & 63;
    const int w    = threadIdx.x >> 6;                // 0..7
    const int q    = lane >> 4, c = lane & 15;
    const int b    = blockIdx.y;
    const int t32  = 127 - (int)blockIdx.x;           // heavy blocks first
    const int row0 = t32 * 32;
    const int grow = b * T_ + row0;
    const int nk   = (t32 >> 1) + 1;                  // 64-key tiles (last=diag)

    _Float16* pl0 = (_Float16*)smem + w * 2304 + c * 72;
    _Float16* pl1 = pl0 + 1152;

    // Q B-frags for both n-tiles, pre-scaled by (1/8)*log2(e)
    const _Float16 qs = (_Float16)0.18033688f;
    half8 bq0 = *(const half8*)(Qh + (size_t)(grow + c) * H_ + q * 8);
    half8 bq1 = *(const half8*)(Qh + (size_t)(grow + c) * H_ + 32 + q * 8);
    half8 bq2 = *(const half8*)(Qh + (size_t)(grow + 16 + c) * H_ + q * 8);
    half8 bq3 = *(const half8*)(Qh + (size_t)(grow + 16 + c) * H_ + 32 + q * 8);
    bq0 *= qs; bq1 *= qs; bq2 *= qs; bq3 *= qs;

    floatx4 o0[4], o1[4];
    #pragma unroll
    for (int i = 0; i < 4; ++i) {
        o0[i] = floatx4{0.f, 0.f, 0.f, 0.f};
        o1[i] = floatx4{0.f, 0.f, 0.f, 0.f};
    }
    float m0 = -3.0e38f, l0 = 0.f, m1 = -3.0e38f, l1 = 0.f;

    for (int kt = w; kt < nk; kt += 8) {
        const int kb = kt * 64;
        const _Float16* Kt = Kpk + ((size_t)b * 64 + kt) * 4096;
        const _Float16* Vt = Vpk + ((size_t)b * 64 + kt) * 4096;

        // K-frags: lane-contiguous 1-KB loads (shared by both n-tiles)
        half8 ka[4], kb8[4];
        #pragma unroll
        for (int mt = 0; mt < 4; ++mt) {
            ka[mt]  = *(const half8*)(Kt + ((size_t)(mt * 2)     * 64 + lane) * 8);
            kb8[mt] = *(const half8*)(Kt + ((size_t)(mt * 2 + 1) * 64 + lane) * 8);
        }
        floatx4 s0[4], s1[4];
        #pragma unroll
        for (int mt = 0; mt < 4; ++mt) {
            floatx4 z = floatx4{0.f, 0.f, 0.f, 0.f};
            z = MFMA16(ka[mt], bq0, z);
            s0[mt] = MFMA16(kb8[mt], bq1, z);
        }
        // V-frags issued here; latency hides behind s1 MFMAs + softmax
        half8 va[4], vb[4];
        #pragma unroll
        for (int mt = 0; mt < 4; ++mt) {
            va[mt] = *(const half8*)(Vt + ((size_t)(mt * 2)     * 64 + lane) * 8);
            vb[mt] = *(const half8*)(Vt + ((size_t)(mt * 2 + 1) * 64 + lane) * 8);
        }
        #pragma unroll
        for (int mt = 0; mt < 4; ++mt) {
            floatx4 z = floatx4{0.f, 0.f, 0.f, 0.f};
            z = MFMA16(ka[mt], bq2, z);
            s1[mt] = MFMA16(kb8[mt], bq3, z);
        }

        if (kt == nk - 1) {                           // causal mask (diag tile)
            #pragma unroll
            for (int mt = 0; mt < 4; ++mt)
                #pragma unroll
                for (int r = 0; r < 4; ++r) {
                    const int key = kb + mt * 16 + q * 4 + r;
                    if (key > row0 + c)      s0[mt][r] = -3.0e38f;
                    if (key > row0 + 16 + c) s1[mt][r] = -3.0e38f;
                }
        }

        // ---- softmax n-tile 0 ----
        {
            float mx = s0[0][0];
            #pragma unroll
            for (int mt = 0; mt < 4; ++mt)
                #pragma unroll
                for (int r = 0; r < 4; ++r) mx = fmaxf(mx, s0[mt][r]);
            mx = fmaxf(mx, __shfl_xor(mx, 16, 64));
            mx = fmaxf(mx, __shfl_xor(mx, 32, 64));
            const float mn    = fmaxf(m0, mx);
            const float alpha = exp2f(m0 - mn);
            float sl = 0.f;
            #pragma unroll
            for (int mt = 0; mt < 4; ++mt) {
                half4_ ph;
                #pragma unroll
                for (int r = 0; r < 4; ++r) {
                    const float p = exp2f(s0[mt][r] - mn);
                    sl += p;
                    ph[r] = (_Float16)p;
                }
                *(half4_*)(pl0 + mt * 16 + q * 4) = ph;
            }
            sl += __shfl_xor(sl, 16, 64);
            sl += __shfl_xor(sl, 32, 64);
            l0 = l0 * alpha + sl;
            m0 = mn;
            #pragma unroll
            for (int mt = 0; mt < 4; ++mt)
                #pragma unroll
                for (int r = 0; r < 4; ++r) o0[mt][r] *= alpha;
        }
        // ---- softmax n-tile 1 ----
        {
            float mx = s1[0][0];
            #pragma unroll
            for (int mt = 0; mt < 4; ++mt)
                #pragma unroll
                for (int r = 0; r < 4; ++r) mx = fmaxf(mx, s1[mt][r]);
            mx = fmaxf(mx, __shfl_xor(mx, 16, 64));
            mx = fmaxf(mx, __shfl_xor(mx, 32, 64));
            const float mn    = fmaxf(m1, mx);
            const float alpha = exp2f(m1 - mn);
            float sl = 0.f;
            #pragma unroll
            for (int mt = 0; mt < 4; ++mt) {
                half4_ ph;
                #pragma unroll
                for (int r = 0; r < 4; ++r) {
                    const float p = exp2f(s1[mt][r] - mn);
                    sl += p;
                    ph[r] = (_Float16)p;
                }
                *(half4_*)(pl1 + mt * 16 + q * 4) = ph;
            }
            sl += __shfl_xor(sl, 16, 64);
            sl += __shfl_xor(sl, 32, 64);
            l1 = l1 * alpha + sl;
            m1 = mn;
            #pragma unroll
            for (int mt = 0; mt < 4; ++mt)
                #pragma unroll
                for (int r = 0; r < 4; ++r) o1[mt][r] *= alpha;
        }

        // P B-frags (DS in-order per wave: reads follow this iter's writes)
        const half8 bp0 = *(const half8*)(pl0 + q * 8);
        const half8 bp1 = *(const half8*)(pl0 + 32 + q * 8);
        const half8 bp2 = *(const half8*)(pl1 + q * 8);
        const half8 bp3 = *(const half8*)(pl1 + 32 + q * 8);

        // O^T += V^T · P^T  (V-frags shared by both n-tiles)
        #pragma unroll
        for (int mt = 0; mt < 4; ++mt) {
            o0[mt] = MFMA16(va[mt], bp0, o0[mt]);
            o0[mt] = MFMA16(vb[mt], bp1, o0[mt]);
            o1[mt] = MFMA16(va[mt], bp2, o1[mt]);
            o1[mt] = MFMA16(vb[mt], bp3, o1[mt]);
        }
    }

    // ---- two-phase flash combine across the 8 waves ----
    float* Ol = (float*)smem;                         // [8][1088]
    float* Ml = (float*)(smem + 34816);               // [8][16]
    float* Ll = (float*)(smem + 35328);               // [8][16]
    #pragma unroll
    for (int ph = 0; ph < 2; ++ph) {
        const float     mm = ph ? m1 : m0;
        const float     ll = ph ? l1 : l0;
        const floatx4* oo  = ph ? o1 : o0;
        __syncthreads();                              // P / prev-phase reads done
        if (q == 0) Ml[w * 16 + c] = mm;
        __syncthreads();
        float M = Ml[c];
        #pragma unroll
        for (int w2 = 1; w2 < 8; ++w2) M = fmaxf(M, Ml[w2 * 16 + c]);
        const float alpha = exp2f(mm - M);            // 0 for empty waves
        if (q == 0) Ll[w * 16 + c] = ll * alpha;
        #pragma unroll
        for (int mt = 0; mt < 4; ++mt)
            #pragma unroll
            for (int r = 0; r < 4; ++r)
                Ol[w * 1088 + (mt * 16 + q * 4 + r) * 17 + c] = oo[mt][r] * alpha;
        __syncthreads();
        float L = 0.f;
        #pragma unroll
        for (int w2 = 0; w2 < 8; ++w2) L += Ll[w2 * 16 + c];
        const float inv = 1.f / L;
        const int h0 = w * 8 + q * 2;
        float ox = 0.f, oy = 0.f;
        #pragma unroll
        for (int w2 = 0; w2 < 8; ++w2) {
            ox += Ol[w2 * 1088 + h0 * 17 + c];
            oy += Ol[w2 * 1088 + (h0 + 1) * 17 + c];
        }
        float2 st; st.x = ox * inv; st.y = oy * inv;
        *(float2*)(out + (size_t)(grow + ph * 16 + c) * H_ + h0) = st;
    }
}

extern "C" void kernel_launch(void* const* d_in, const int* in_sizes, int n_in,
                              void* d_out, int out_size, void* d_ws, size_t ws_size,
                              hipStream_t stream) {
    const float* x  = (const float*)d_in[0];
    const float* Wq = (const float*)d_in[1];
    const float* Wk = (const float*)d_in[2];
    const float* Wv = (const float*)d_in[3];
    float* out = (float*)d_out;

    _Float16* ws = (_Float16*)d_ws;
    _Float16* Wt2 = ws;                               //   192*1024 = 196608
    _Float16* Qh  = ws + 196608;                      // 16384*64  = 1048576
    _Float16* Kpk = Qh + 1048576;                     // [4][64][4096]
    _Float16* Vpk = Kpk + 1048576;                    // [4][64][4096]

    hipLaunchKernelGGL(pack_w_kn, dim3(768), dim3(256), 0, stream, Wq, Wk, Wv, Wt2);
    hipLaunchKernelGGL(qkv_kn, dim3((B_ * T_) / 32), dim3(256), 0, stream,
                       x, Wt2, Qh, Kpk, Vpk);
    hipLaunchKernelGGL(attn_kn, dim3(T_ / 32, B_), dim3(512), 0, stream,
                       Qh, Kpk, Vpk, out);
}

// Round 8
// 146.172 us; speedup vs baseline: 1.0424x; 1.0424x over previous
//
#include <hip/hip_runtime.h>

#define B_ 4
#define T_ 4096
#define C_ 1024
#define H_ 64

typedef _Float16 half8  __attribute__((ext_vector_type(8)));
typedef _Float16 half4_ __attribute__((ext_vector_type(4)));
typedef float    floatx4 __attribute__((ext_vector_type(4)));

#define MFMA16(a, b, c) __builtin_amdgcn_mfma_f32_16x16x32_f16(a, b, c, 0, 0, 0)

// ---------------------------------------------------------------------------
// Kernel 1: pack W into MFMA-fragment order (lane-contiguous A-frags):
// Wt2[(((mt*16 + j)*2 + f)*64 + lane)*8 + jj] <- W[k][h'],
//   k = j*64 + f*32 + (lane>>4)*8 + jj,  h' = mt*16 + (lane&15)  (mt 0..11)
// ---------------------------------------------------------------------------
__global__ __launch_bounds__(256) void pack_w_kn(
    const float* __restrict__ Wq, const float* __restrict__ Wk,
    const float* __restrict__ Wv, _Float16* __restrict__ Wt2)
{
    const int idx  = blockIdx.x * 256 + threadIdx.x;  // 0 .. 196607
    const int mt   = idx >> 14;
    const int j    = (idx >> 10) & 15;
    const int f    = (idx >> 9) & 1;
    const int lane = (idx >> 3) & 63;
    const int jj   = idx & 7;
    const int q = lane >> 4, c = lane & 15;
    const int k  = j * 64 + f * 32 + q * 8 + jj;
    const int hp = mt * 16 + c;                       // 0..191
    const float* W = (hp < 64) ? Wq : (hp < 128) ? Wk : Wv;
    Wt2[idx] = (_Float16)W[k * H_ + (hp & 63)];
}

// ---------------------------------------------------------------------------
// Kernel 2: fused QKV projection (round-6 structure).  Block = 512 thr,
// BM=32 rows, 16 K-steps of 64, x dbuf-staged in LDS.  Wave (nt, mg):
// n-half nt, m-group mg (3 m-tiles).  Outputs: Q, K, V ALL in per-tile
// fragment-packed layouts (Q per 16-row q-tile; K/V per 64-key tile).
// ---------------------------------------------------------------------------
__global__ __launch_bounds__(512) void qkv_kn(
    const float* __restrict__ x, const _Float16* __restrict__ Wt2,
    _Float16* __restrict__ Qpk, _Float16* __restrict__ Kpk,
    _Float16* __restrict__ Vpk)
{
    __shared__ _Float16 xs[2][32][72];                // 9216 B
    const int tid  = threadIdx.x;
    const int lane = tid & 63, w = tid >> 6;
    const int q    = lane >> 4, c = lane & 15;
    const int nt   = w & 1;                           // n-half (16 rows)
    const int mg   = w >> 1;                          // m-group (3 m-tiles)
    const int row0 = blockIdx.x * 32;

    const int srow = tid >> 4, scol = (tid & 15) * 4;
    const float* xg = x + (size_t)(row0 + srow) * C_ + scol;

    floatx4 acc[3];
    #pragma unroll
    for (int i = 0; i < 3; ++i) acc[i] = floatx4{0.f, 0.f, 0.f, 0.f};

    float4 g = *(const float4*)xg;                    // preload tile 0

    for (int j = 0; j < 16; ++j) {
        half4_ hv;
        hv[0] = (_Float16)g.x; hv[1] = (_Float16)g.y;
        hv[2] = (_Float16)g.z; hv[3] = (_Float16)g.w;
        *(half4_*)(&xs[j & 1][srow][scol]) = hv;
        __syncthreads();
        if (j < 15) g = *(const float4*)(xg + (j + 1) * 64);

        const _Float16* xrow = &xs[j & 1][nt * 16 + c][q * 8];
        const half8 b0 = *(const half8*)xrow;
        const half8 b1 = *(const half8*)(xrow + 32);

        // A-frags: 6 lane-contiguous 1-KB loads from L2-hot packed Wt2
        half8 a[6];
        #pragma unroll
        for (int i = 0; i < 3; ++i) {
            const size_t fb = ((size_t)((mg * 3 + i) * 16 + j) * 2) * 512 + lane * 8;
            a[i * 2]     = *(const half8*)(Wt2 + fb);
            a[i * 2 + 1] = *(const half8*)(Wt2 + fb + 512);
        }
        #pragma unroll
        for (int i = 0; i < 3; ++i) {
            acc[i] = MFMA16(a[i * 2],     b0, acc[i]);
            acc[i] = MFMA16(a[i * 2 + 1], b1, acc[i]);
        }
    }

    // epilogue: lane col = x-row (row0+nt*16+c); rows h' = gi*16+q*4+r
    const int row = row0 + nt * 16 + c;
    const int b = row >> 12, t4 = row & (T_ - 1);
    const int kt = t4 >> 6;
    const size_t tbase = ((size_t)b * 64 + kt) * 4096;
    const int mtk = (t4 >> 4) & 3;                    // key-tile m-row group
    const int kk  = t4 & 63;                          // key pos in tile

    #pragma unroll
    for (int i = 0; i < 3; ++i) {
        const int gi = mg * 3 + i;                    // m-tile 0..11
        if (gi < 4) {                                 // Q fragment-packed (B-frag)
            half4_ v;
            #pragma unroll
            for (int r = 0; r < 4; ++r) v[r] = (_Float16)acc[i][r];
            const int qa = (gi * 2 + (q >> 1)) & 3;   // (h>>3)&3, h=gi*16+q*4+r
            *(half4_*)(Qpk + ((size_t)b * 256 + (t4 >> 4)) * 1024
                       + ((size_t)((gi >> 1) * 64 + qa * 16 + c)) * 8
                       + (q & 1) * 4) = v;
        } else if (gi < 8) {                          // K fragment-packed
            half4_ v;
            #pragma unroll
            for (int r = 0; r < 4; ++r) v[r] = (_Float16)acc[i][r];
            const int e  = gi - 4;                    // h = e*16 + q*4 + r
            const int f  = e >> 1;
            const int qa = (e * 2 + (q >> 1)) & 3;
            *(half4_*)(Kpk + tbase + ((size_t)(mtk * 2 + f) * 64 + qa * 16 + c) * 8
                       + (q & 1) * 4) = v;
        } else {                                      // V fragment-packed
            const int mtv = gi - 8;
            const int qa = (kk >> 3) & 3, fv = kk >> 5, jv = kk & 7;
            #pragma unroll
            for (int r = 0; r < 4; ++r) {
                const int cv = q * 4 + r;             // h & 15
                Vpk[tbase + ((size_t)(mtv * 2 + fv) * 64 + qa * 16 + cv) * 8 + jv]
                    = (_Float16)acc[i][r];
            }
        }
    }
}

// ---------------------------------------------------------------------------
// Kernel 3: causal flash attention (round-6 structure), 8-way in-block
// split-K, fragment-packed Q/K/V (every frag load = base + lane*16).
// BALANCE FIX: t = (by&1) ? bx : 255-bx -> each CU's 4 co-resident blocks
// pair heavy(255-i) with light(i): per-CU work constant ~130 iters (was 256).
// ---------------------------------------------------------------------------
__global__ __launch_bounds__(512, 4) void attn_kn(
    const _Float16* __restrict__ Qpk, const _Float16* __restrict__ Kpk,
    const _Float16* __restrict__ Vpk, float* __restrict__ out)
{
    __shared__ __align__(16) char smem[36864];
    const int lane = threadIdx.x & 63;
    const int w    = threadIdx.x >> 6;                // 0..7
    const int q    = lane >> 4, c = lane & 15;
    const int b    = blockIdx.y;
    const int t    = (blockIdx.y & 1) ? (int)blockIdx.x
                                      : 255 - (int)blockIdx.x;
    const int row0 = t * 16;
    const int grow = b * T_ + row0;
    const int nk   = (t >> 2) + 1;                    // 64-key tiles (last=diag)

    _Float16* Pw = (_Float16*)smem + w * 2304;        // wave's 2 P buffers

    // Q B-frags: lane-contiguous packed load.  Pre-scale by (1/8)*log2(e).
    const _Float16* qp = Qpk + ((size_t)b * 256 + t) * 1024 + (size_t)lane * 8;
    half8 bq0 = *(const half8*)qp;
    half8 bq1 = *(const half8*)(qp + 512);
    const _Float16 qs = (_Float16)0.18033688f;
    bq0 *= qs; bq1 *= qs;

    floatx4 o[4];
    #pragma unroll
    for (int i = 0; i < 4; ++i) o[i] = floatx4{0.f, 0.f, 0.f, 0.f};
    float m = -3.0e38f, l = 0.f;

    for (int kt = w; kt < nk; kt += 8) {
        const int kb = kt * 64;
        const _Float16* Kt = Kpk + ((size_t)b * 64 + kt) * 4096;
        const _Float16* Vt = Vpk + ((size_t)b * 64 + kt) * 4096;
        half8 a0[4], a1[4];

        // K-frags: lane-contiguous packed loads
        #pragma unroll
        for (int mt = 0; mt < 4; ++mt) {
            a0[mt] = *(const half8*)(Kt + ((size_t)(mt * 2)     * 64 + lane) * 8);
            a1[mt] = *(const half8*)(Kt + ((size_t)(mt * 2 + 1) * 64 + lane) * 8);
        }
        floatx4 s[4];
        #pragma unroll
        for (int mt = 0; mt < 4; ++mt) {
            floatx4 z = floatx4{0.f, 0.f, 0.f, 0.f};
            z = MFMA16(a0[mt], bq0, z);
            s[mt] = MFMA16(a1[mt], bq1, z);
        }
        // V-frags issued now; latency hides behind softmax
        #pragma unroll
        for (int mt = 0; mt < 4; ++mt) {
            a0[mt] = *(const half8*)(Vt + ((size_t)(mt * 2)     * 64 + lane) * 8);
            a1[mt] = *(const half8*)(Vt + ((size_t)(mt * 2 + 1) * 64 + lane) * 8);
        }

        if (kt == nk - 1) {                           // causal mask (diag tile)
            #pragma unroll
            for (int mt = 0; mt < 4; ++mt)
                #pragma unroll
                for (int r = 0; r < 4; ++r)
                    if (kb + mt * 16 + q * 4 + r > row0 + c) s[mt][r] = -3.0e38f;
        }

        // online softmax; lane holds 16 scores of ONE q-row
        float mx = s[0][0];
        #pragma unroll
        for (int mt = 0; mt < 4; ++mt)
            #pragma unroll
            for (int r = 0; r < 4; ++r) mx = fmaxf(mx, s[mt][r]);
        mx = fmaxf(mx, __shfl_xor(mx, 16, 64));
        mx = fmaxf(mx, __shfl_xor(mx, 32, 64));
        const float mn    = fmaxf(m, mx);
        const float alpha = exp2f(m - mn);
        float p[4][4];
        float sl = 0.f;
        #pragma unroll
        for (int mt = 0; mt < 4; ++mt)
            #pragma unroll
            for (int r = 0; r < 4; ++r) {
                p[mt][r] = exp2f(s[mt][r] - mn);
                sl += p[mt][r];
            }
        sl += __shfl_xor(sl, 16, 64);
        sl += __shfl_xor(sl, 32, 64);
        l = l * alpha + sl;
        m = mn;
        #pragma unroll
        for (int mt = 0; mt < 4; ++mt)
            #pragma unroll
            for (int r = 0; r < 4; ++r) o[mt][r] *= alpha;

        // P^T -> wave-private LDS (double-buffered), reload as B-frags
        _Float16* pl = Pw + ((kt >> 3) & 1) * 1152 + c * 72;
        #pragma unroll
        for (int mt = 0; mt < 4; ++mt) {
            half4_ ph;
            #pragma unroll
            for (int r = 0; r < 4; ++r) ph[r] = (_Float16)p[mt][r];
            *(half4_*)(pl + mt * 16 + q * 4) = ph;
        }
        const half8 bp0 = *(const half8*)(pl + q * 8);
        const half8 bp1 = *(const half8*)(pl + 32 + q * 8);

        // O^T += V^T · P^T
        #pragma unroll
        for (int mt = 0; mt < 4; ++mt) {
            o[mt] = MFMA16(a0[mt], bp0, o[mt]);
            o[mt] = MFMA16(a1[mt], bp1, o[mt]);
        }
    }

    // ---- flash combine across the 8 waves (overlay LDS after sync) ----
    __syncthreads();
    float* Ol = (float*)smem;                         // [8][1088]
    float* Ml = (float*)(smem + 34816);               // [8][16]
    float* Ll = (float*)(smem + 35328);               // [8][16]
    if (q == 0) Ml[w * 16 + c] = m;
    __syncthreads();
    float M = Ml[c];
    #pragma unroll
    for (int w2 = 1; w2 < 8; ++w2) M = fmaxf(M, Ml[w2 * 16 + c]);
    const float alpha = exp2f(m - M);                 // 0 for empty waves
    if (q == 0) Ll[w * 16 + c] = l * alpha;
    #pragma unroll
    for (int mt = 0; mt < 4; ++mt)
        #pragma unroll
        for (int r = 0; r < 4; ++r)
            Ol[w * 1088 + (mt * 16 + q * 4 + r) * 17 + c] = o[mt][r] * alpha;
    __syncthreads();

    float L = 0.f;
    #pragma unroll
    for (int w2 = 0; w2 < 8; ++w2) L += Ll[w2 * 16 + c];
    const float inv = 1.f / L;
    const int h0 = w * 8 + q * 2;
    float ox = 0.f, oy = 0.f;
    #pragma unroll
    for (int w2 = 0; w2 < 8; ++w2) {
        ox += Ol[w2 * 1088 + h0 * 17 + c];
        oy += Ol[w2 * 1088 + (h0 + 1) * 17 + c];
    }
    float2 st; st.x = ox * inv; st.y = oy * inv;
    *(float2*)(out + (size_t)(grow + c) * H_ + h0) = st;
}

extern "C" void kernel_launch(void* const* d_in, const int* in_sizes, int n_in,
                              void* d_out, int out_size, void* d_ws, size_t ws_size,
                              hipStream_t stream) {
    const float* x  = (const float*)d_in[0];
    const float* Wq = (const float*)d_in[1];
    const float* Wk = (const float*)d_in[2];
    const float* Wv = (const float*)d_in[3];
    float* out = (float*)d_out;

    _Float16* ws = (_Float16*)d_ws;
    _Float16* Wt2 = ws;                               //   192*1024 = 196608
    _Float16* Qpk = ws + 196608;                      // [4][256][1024]
    _Float16* Kpk = Qpk + 1048576;                    // [4][64][4096]
    _Float16* Vpk = Kpk + 1048576;                    // [4][64][4096]

    hipLaunchKernelGGL(pack_w_kn, dim3(768), dim3(256), 0, stream, Wq, Wk, Wv, Wt2);
    hipLaunchKernelGGL(qkv_kn, dim3((B_ * T_) / 32), dim3(512), 0, stream,
                       x, Wt2, Qpk, Kpk, Vpk);
    hipLaunchKernelGGL(attn_kn, dim3(T_ / 16, B_), dim3(512), 0, stream,
                       Qpk, Kpk, Vpk, out);
}